// Round 2
// baseline (570.800 us; speedup 1.0000x reference)
//
#include <hip/hip_runtime.h>
#include <hip/hip_bf16.h>
#include <cstdint>
#include <cstddef>

// ---------------- problem constants ----------------
#define D_MODEL 1024
#define D_STATE 64
#define D_INNER 2048
#define BATCH   4
#define SEQ     2048
#define MROWS   (BATCH*SEQ)      // 8192
#define CHUNK   32               // scan chunk length
#define NCHUNK  (SEQ/CHUNK)      // 64 chunks per batch

typedef __bf16 bf16x8 __attribute__((ext_vector_type(8)));
typedef float  f32x4  __attribute__((ext_vector_type(4)));

__device__ __forceinline__ float bf2f(unsigned short u) {
    union { unsigned int i; float f; } v; v.i = ((unsigned int)u) << 16; return v.f;
}
__device__ __forceinline__ unsigned short f2bf(float f) {
    union { float f; unsigned int i; } v; v.f = f;
    unsigned int r = v.i + 0x7fff + ((v.i >> 16) & 1);   // round-to-nearest-even
    return (unsigned short)(r >> 16);
}
__device__ __forceinline__ float lo16(unsigned u){ return bf2f((unsigned short)(u & 0xffffu)); }
__device__ __forceinline__ float hi16(unsigned u){ return bf2f((unsigned short)(u >> 16)); }
__device__ __forceinline__ unsigned pack2(float a, float b){
    return (unsigned)f2bf(a) | ((unsigned)f2bf(b) << 16);
}

// ---------------- f32 -> bf16 bulk convert (4 elems/thread) ----------------
__global__ __launch_bounds__(256) void f32_to_bf16(const float* __restrict__ in,
                                                   unsigned short* __restrict__ out) {
    size_t i = ((size_t)blockIdx.x * 256 + threadIdx.x) * 4;
    float4 v = *(const float4*)(in + i);
    uint2 o; o.x = pack2(v.x, v.y); o.y = pack2(v.z, v.w);
    *(uint2*)(out + i) = o;
}

// ---------------- transpose f32 -> bf16: out[c][r] = bf16(in[r][c]) ----------------
__global__ void transpose_f32_bf16(const float* __restrict__ in,
                                   unsigned short* __restrict__ out, int rows, int cols) {
    __shared__ float t[32][33];
    int bx = blockIdx.x * 32, by = blockIdx.y * 32;
    int tx = threadIdx.x, ty = threadIdx.y;
    int r = by + ty, c = bx + tx;
    if (r < rows && c < cols) t[ty][tx] = in[(size_t)r * cols + c];
    __syncthreads();
    int ro = bx + ty, co = by + tx;
    if (ro < cols && co < rows) out[(size_t)ro * rows + co] = f2bf(t[tx][ty]);
}

// ---------------- pack W_xp (f32): cols 1..128 -> bf16 [2048][128]; col 0 -> w0 (f32) ----
__global__ void pack_wxp(const float* __restrict__ wxp,
                         unsigned short* __restrict__ packed, float* __restrict__ w0f) {
    int k = blockIdx.x * 256 + threadIdx.x;
    if (k < D_INNER) {
        const float* row = wxp + (size_t)k * 129;
        w0f[k] = row[0];
        for (int j = 0; j < 128; ++j) packed[(size_t)k * 128 + j] = f2bf(row[1 + j]);
    }
}

// ---------------- MFMA GEMM (TN): C[M][N] = A[M][K] @ BT[N][K]^T ----------------
// 128x128 block tile, BK=32, 256 threads (4 waves, 2x2), global_load_lds(16B).
// Requires M%128==0, N%128==0, K%32==0, lda%8==0, ldb%8==0.
#define BM 128
#define BN 128
#define BK 32
enum { EPI_PLAIN = 0, EPI_STORE_T = 1, EPI_MUL_XI = 2, EPI_F32OUT = 3 };

__device__ __forceinline__ void gload_lds16(const void* g, void* l) {
    __builtin_amdgcn_global_load_lds((const __attribute__((address_space(1))) void*)g,
                                     (__attribute__((address_space(3))) void*)l, 16, 0, 0);
}

template<int EPI>
__global__ __launch_bounds__(256) void gemm_tn(
    const unsigned short* __restrict__ A,   // [M][K] lda (bf16)
    const unsigned short* __restrict__ BT,  // [N][K] ldb (bf16)
    void* __restrict__ Cv,                  // [M][N] ldc (bf16; [N][M] if STORE_T; f32 if F32OUT)
    const unsigned short* __restrict__ XI, int ldxi,
    int M, int N, int K, int lda, int ldb, int ldc)
{
    __shared__ __align__(16) unsigned short As[BM * BK];
    __shared__ __align__(16) unsigned short Bs[BN * BK];
    const int tid  = threadIdx.x;
    const int wave = tid >> 6, lane = tid & 63;
    const int row0 = blockIdx.y * BM, col0 = blockIdx.x * BN;
    const int wr = (wave >> 1) * 64, wc = (wave & 1) * 64;
    const int srow = lane >> 2;          // 0..15
    const int scol = (lane & 3) * 8;     // 0,8,16,24

    f32x4 acc[4][4];
    #pragma unroll
    for (int i = 0; i < 4; ++i)
        #pragma unroll
        for (int j = 0; j < 4; ++j)
            #pragma unroll
            for (int r = 0; r < 4; ++r) acc[i][j][r] = 0.0f;

    for (int k0 = 0; k0 < K; k0 += BK) {
        #pragma unroll
        for (int qi = 0; qi < 2; ++qi) {
            int q = wave * 2 + qi;   // 0..7: 16-row group of the 128-row tile
            const unsigned short* gA = A  + (size_t)(row0 + q*16 + srow) * lda + (k0 + scol);
            const unsigned short* gB = BT + (size_t)(col0 + q*16 + srow) * ldb + (k0 + scol);
            gload_lds16(gA, &As[q * 512]);   // lane l lands at +l*16B (contiguous row-major)
            gload_lds16(gB, &Bs[q * 512]);
        }
        __syncthreads();
        bf16x8 af[4], bfr[4];
        #pragma unroll
        for (int t = 0; t < 4; ++t) {
            af[t]  = *(const bf16x8*)&As[(wr + t*16 + (lane & 15)) * BK + (lane >> 4) * 8];
            bfr[t] = *(const bf16x8*)&Bs[(wc + t*16 + (lane & 15)) * BK + (lane >> 4) * 8];
        }
        #pragma unroll
        for (int i = 0; i < 4; ++i)
            #pragma unroll
            for (int j = 0; j < 4; ++j)
                acc[i][j] = __builtin_amdgcn_mfma_f32_16x16x32_bf16(af[i], bfr[j], acc[i][j], 0, 0, 0);
        __syncthreads();
    }

    const int r0 = (lane >> 4) * 4, cl = lane & 15;
    #pragma unroll
    for (int i = 0; i < 4; ++i) {
        #pragma unroll
        for (int j = 0; j < 4; ++j) {
            #pragma unroll
            for (int r = 0; r < 4; ++r) {
                int gr = row0 + wr + i*16 + r0 + r;
                int gc = col0 + wc + j*16 + cl;
                float v = acc[i][j][r];
                if (EPI == EPI_MUL_XI) v *= bf2f(XI[(size_t)gr * ldxi + gc]);
                if (EPI == EPI_F32OUT)       ((float*)Cv)[(size_t)gr * ldc + gc] = v;
                else if (EPI == EPI_STORE_T) ((unsigned short*)Cv)[(size_t)gc * ldc + gr] = f2bf(v);
                else                         ((unsigned short*)Cv)[(size_t)gr * ldc + gc] = f2bf(v);
            }
        }
    }
}

// ---------------- delta: dA[m] = softplus(xi[m,:]. w0) * A ; abar = exp(dA) ----------------
__global__ __launch_bounds__(256) void delta_kernel(
    const unsigned short* __restrict__ xz, const float* __restrict__ w0f,
    const float* __restrict__ A_log,
    float* __restrict__ dA, float* __restrict__ abar)
{
    int row  = blockIdx.x * 4 + (threadIdx.x >> 6);
    int lane = threadIdx.x & 63;
    const unsigned short* xi = xz + (size_t)row * (2 * D_INNER);
    float s = 0.f;
    #pragma unroll
    for (int step = 0; step < 4; ++step) {
        int oct = step * 64 + lane;          // 256 octets of 8 bf16
        uint4 u = *(const uint4*)(xi + oct * 8);
        const float4* pw = (const float4*)(w0f + oct * 8);
        float4 wa = pw[0], wb = pw[1];
        s += lo16(u.x)*wa.x + hi16(u.x)*wa.y + lo16(u.y)*wa.z + hi16(u.y)*wa.w
           + lo16(u.z)*wb.x + hi16(u.z)*wb.y + lo16(u.w)*wb.z + hi16(u.w)*wb.w;
    }
    #pragma unroll
    for (int off = 32; off > 0; off >>= 1) s += __shfl_xor(s, off);
    if (lane == 0) {
        float Av = -expf(A_log[0]);
        float d  = (s > 20.f) ? s : log1pf(expf(s));
        float da = d * Av;
        dA[row] = da;
        abar[row] = expf(da);
    }
}

// ---------------- chunk decay products: P[b*NC+j] = exp(sum dA over chunk) ----------------
__global__ void chunk_prod(const float* __restrict__ dA, float* __restrict__ P) {
    int idx = threadIdx.x;                    // 0..255 = b*NCHUNK + j
    float s = 0.f;
    #pragma unroll
    for (int t = 0; t < CHUNK; ++t) s += dA[idx * CHUNK + t];
    P[idx] = expf(s);
}

// ---------------- scan phase 1: per-chunk local scan (h init 0) -> carry ----------------
__global__ __launch_bounds__(256) void scan_local(
    const unsigned short* __restrict__ bxi, const float* __restrict__ abar,
    float* __restrict__ carry)
{
    int cb = blockIdx.x, j = blockIdx.y, b = blockIdx.z;
    int c0 = cb * 1024 + threadIdx.x * 4;
    int srow = b * SEQ + j * CHUNK;
    const float* ab = abar + srow;
    const unsigned short* p = bxi + (size_t)srow * D_INNER + c0;
    float h0 = 0.f, h1 = 0.f, h2 = 0.f, h3 = 0.f;
    #pragma unroll 8
    for (int t = 0; t < CHUNK; ++t) {
        float a = ab[t];
        uint2 u = *(const uint2*)(p + (size_t)t * D_INNER);
        h0 = fmaf(a, h0, lo16(u.x)); h1 = fmaf(a, h1, hi16(u.x));
        h2 = fmaf(a, h2, lo16(u.y)); h3 = fmaf(a, h3, hi16(u.y));
    }
    *(float4*)(carry + ((size_t)(b * NCHUNK + j)) * D_INNER + c0) = make_float4(h0, h1, h2, h3);
}

// ---------------- scan phase 2: inter-chunk scan; carry <- exclusive prefix (h-init) ------
__global__ __launch_bounds__(256) void scan_chunks(float* __restrict__ carry,
                                                   const float* __restrict__ P) {
    int c = blockIdx.x * 256 + threadIdx.x;
    int b = blockIdx.y;
    float H = 0.f;
    for (int j = 0; j < NCHUNK; ++j) {
        size_t idx = ((size_t)(b * NCHUNK + j)) * D_INNER + c;
        float cr = carry[idx];
        carry[idx] = H;                         // exclusive: h-init for chunk j
        H = P[b * NCHUNK + j] * H + cr;
    }
}

// ---------------- scan phase 3: re-scan with init + fused epilogue -> ypre ----------------
// NOTE: ypre aliases bxi (element read happens before write, same thread) -> no restrict
__global__ __launch_bounds__(256) void scan_final(
    const unsigned short* bxi, const unsigned short* __restrict__ cmat,
    const unsigned short* __restrict__ xz, const float* __restrict__ Dvf,
    const float* __restrict__ abar, const float* __restrict__ carry,
    unsigned short* ypre)
{
    int cb = blockIdx.x, j = blockIdx.y, b = blockIdx.z;
    int c0 = cb * 1024 + threadIdx.x * 4;
    int srow = b * SEQ + j * CHUNK;
    float4 hin = *(const float4*)(carry + ((size_t)(b * NCHUNK + j)) * D_INNER + c0);
    float h0 = hin.x, h1 = hin.y, h2 = hin.z, h3 = hin.w;
    float4 dv = *(const float4*)(Dvf + c0);
    float d0 = dv.x, d1 = dv.y, d2 = dv.z, d3 = dv.w;
    const float* ab = abar + srow;
    #pragma unroll 4
    for (int t = 0; t < CHUNK; ++t) {
        size_t m = (size_t)(srow + t);
        float a = ab[t];
        uint2 ub = *(const uint2*)(bxi + m * D_INNER + c0);
        h0 = fmaf(a, h0, lo16(ub.x)); h1 = fmaf(a, h1, hi16(ub.x));
        h2 = fmaf(a, h2, lo16(ub.y)); h3 = fmaf(a, h3, hi16(ub.y));
        uint2 uc = *(const uint2*)(cmat + m * D_INNER + c0);
        uint2 ux = *(const uint2*)(xz + m * (2 * D_INNER) + c0);
        uint2 uz = *(const uint2*)(xz + m * (2 * D_INNER) + D_INNER + c0);
        float y0 = lo16(uc.x) * h0 + d0 * lo16(ux.x);
        float y1 = hi16(uc.x) * h1 + d1 * hi16(ux.x);
        float y2 = lo16(uc.y) * h2 + d2 * lo16(ux.y);
        float y3 = hi16(uc.y) * h3 + d3 * hi16(ux.y);
        float z0 = lo16(uz.x), z1 = hi16(uz.x), z2 = lo16(uz.y), z3 = hi16(uz.y);
        y0 *= z0 / (1.f + expf(-z0)); y1 *= z1 / (1.f + expf(-z1));
        y2 *= z2 / (1.f + expf(-z2)); y3 *= z3 / (1.f + expf(-z3));
        uint2 o; o.x = pack2(y0, y1); o.y = pack2(y2, y3);
        *(uint2*)(ypre + m * D_INNER + c0) = o;
    }
}

// ---------------- launcher ----------------
extern "C" void kernel_launch(void* const* d_in, const int* in_sizes, int n_in,
                              void* d_out, int out_size, void* d_ws, size_t ws_size,
                              hipStream_t stream) {
    const float* x     = (const float*)d_in[0];   // [8192][1024]
    const float* W_in  = (const float*)d_in[1];   // [1024][4096]
    const float* W_xp  = (const float*)d_in[2];   // [2048][129]
    const float* W_B   = (const float*)d_in[3];   // [64][2048]
    const float* W_C   = (const float*)d_in[4];   // [64][2048]
    const float* W_out = (const float*)d_in[5];   // [2048][1024]
    const float* Dv    = (const float*)d_in[6];   // [2048]
    const float* A_log = (const float*)d_in[7];   // [1]
    float* out = (float*)d_out;                   // [8192][1024] f32

    // workspace layout (256B aligned blocks)
    size_t off = 0;
    auto alloc = [&](size_t bytes) {
        void* p = (char*)d_ws + off; off += (bytes + 255) & ~(size_t)255; return p;
    };
    unsigned short* xbf     = (unsigned short*)alloc((size_t)MROWS * D_MODEL * 2);     // 16.8MB
    unsigned short* xz      = (unsigned short*)alloc((size_t)MROWS * 2 * D_INNER * 2); // 67MB
    unsigned short* bxi     = (unsigned short*)alloc((size_t)MROWS * D_INNER * 2);     // 33.5MB (also ypre)
    unsigned short* cmat    = (unsigned short*)alloc((size_t)MROWS * D_INNER * 2);     // 33.5MB
    unsigned short* winT    = (unsigned short*)alloc((size_t)4096 * 1024 * 2);         // 8.4MB
    unsigned short* woutT   = (unsigned short*)alloc((size_t)1024 * 2048 * 2);         // 4.2MB
    unsigned short* wbT     = (unsigned short*)alloc((size_t)2048 * 64 * 2);
    unsigned short* wcT     = (unsigned short*)alloc((size_t)2048 * 64 * 2);
    unsigned short* wxpPack = (unsigned short*)alloc((size_t)2048 * 128 * 2);
    unsigned short* wxbT    = (unsigned short*)alloc((size_t)2048 * 2048 * 2);         // 8.4MB
    unsigned short* wxcT    = (unsigned short*)alloc((size_t)2048 * 2048 * 2);         // 8.4MB
    float* w0f   = (float*)alloc(2048 * 4);
    float* dA    = (float*)alloc(MROWS * 4);
    float* abar  = (float*)alloc(MROWS * 4);
    float* P     = (float*)alloc(BATCH * NCHUNK * 4);
    float* carry = (float*)alloc((size_t)BATCH * NCHUNK * D_INNER * 4);                // 2MB
    (void)ws_size; (void)n_in; (void)in_sizes; (void)out_size;

    // convert x to bf16: 8192*1024 / (256*4) = 8192 blocks
    hipLaunchKernelGGL(f32_to_bf16, dim3((MROWS * D_MODEL) / 1024), dim3(256), 0, stream, x, xbf);

    dim3 tb(32, 32);
    hipLaunchKernelGGL(transpose_f32_bf16, dim3(4096/32, 1024/32), tb, 0, stream, W_in,  winT, 1024, 4096);
    hipLaunchKernelGGL(transpose_f32_bf16, dim3(1024/32, 2048/32), tb, 0, stream, W_out, woutT, 2048, 1024);
    hipLaunchKernelGGL(transpose_f32_bf16, dim3(2048/32, 64/32),   tb, 0, stream, W_B,   wbT, 64, 2048);
    hipLaunchKernelGGL(transpose_f32_bf16, dim3(2048/32, 64/32),   tb, 0, stream, W_C,   wcT, 64, 2048);
    hipLaunchKernelGGL(pack_wxp, dim3(8), dim3(256), 0, stream, W_xp, wxpPack, w0f);

    // W_xB^T = (Wxp[:,1:65] @ W_B)^T  [2048][2048];  same for C
    hipLaunchKernelGGL((gemm_tn<EPI_STORE_T>), dim3(16,16), dim3(256), 0, stream,
                       wxpPack,      wbT, (void*)wxbT, (const unsigned short*)nullptr, 0,
                       2048, 2048, 64, 128, 64, 2048);
    hipLaunchKernelGGL((gemm_tn<EPI_STORE_T>), dim3(16,16), dim3(256), 0, stream,
                       wxpPack + 64, wcT, (void*)wxcT, (const unsigned short*)nullptr, 0,
                       2048, 2048, 64, 128, 64, 2048);

    // xz = x @ W_in   [8192][4096]
    hipLaunchKernelGGL((gemm_tn<EPI_PLAIN>), dim3(4096/BN, MROWS/BM), dim3(256), 0, stream,
                       xbf, winT, (void*)xz, (const unsigned short*)nullptr, 0,
                       MROWS, 4096, 1024, 1024, 1024, 4096);

    // delta / abar
    hipLaunchKernelGGL(delta_kernel, dim3(MROWS/4), dim3(256), 0, stream, xz, w0f, A_log, dA, abar);

    // bxi = (xi @ W_xB) * xi ;  cmat = xi @ W_xC
    hipLaunchKernelGGL((gemm_tn<EPI_MUL_XI>), dim3(D_INNER/BN, MROWS/BM), dim3(256), 0, stream,
                       xz, wxbT, (void*)bxi, xz, 2*D_INNER,
                       MROWS, D_INNER, D_INNER, 2*D_INNER, D_INNER, D_INNER);
    hipLaunchKernelGGL((gemm_tn<EPI_PLAIN>), dim3(D_INNER/BN, MROWS/BM), dim3(256), 0, stream,
                       xz, wxcT, (void*)cmat, (const unsigned short*)nullptr, 0,
                       MROWS, D_INNER, D_INNER, 2*D_INNER, D_INNER, D_INNER);

    // chunked scan + fused epilogue
    hipLaunchKernelGGL(chunk_prod, dim3(1), dim3(BATCH*NCHUNK), 0, stream, dA, P);
    hipLaunchKernelGGL(scan_local,  dim3(2, NCHUNK, BATCH), dim3(256), 0, stream, bxi, abar, carry);
    hipLaunchKernelGGL(scan_chunks, dim3(D_INNER/256, BATCH), dim3(256), 0, stream, carry, P);
    hipLaunchKernelGGL(scan_final,  dim3(2, NCHUNK, BATCH), dim3(256), 0, stream,
                       bxi, cmat, xz, Dv, abar, carry, bxi /*ypre aliases bxi*/);

    // out = ypre @ W_out   [8192][1024] f32
    hipLaunchKernelGGL((gemm_tn<EPI_F32OUT>), dim3(1024/BN, MROWS/BM), dim3(256), 0, stream,
                       bxi, woutT, (void*)out, (const unsigned short*)nullptr, 0,
                       MROWS, 1024, D_INNER, D_INNER, D_INNER, 1024);
}

// Round 3
// 399.949 us; speedup vs baseline: 1.4272x; 1.4272x over previous
//
#include <hip/hip_runtime.h>
#include <hip/hip_bf16.h>
#include <cstdint>
#include <cstddef>

// ---------------- problem constants ----------------
#define D_MODEL 1024
#define D_STATE 64
#define D_INNER 2048
#define BATCH   4
#define SEQ     2048
#define MROWS   (BATCH*SEQ)      // 8192
#define CHUNK   32               // scan chunk length
#define NCHUNK  (SEQ/CHUNK)      // 64 chunks per batch

typedef __bf16 bf16x8 __attribute__((ext_vector_type(8)));
typedef float  f32x4  __attribute__((ext_vector_type(4)));

__device__ __forceinline__ float bf2f(unsigned short u) {
    union { unsigned int i; float f; } v; v.i = ((unsigned int)u) << 16; return v.f;
}
__device__ __forceinline__ unsigned short f2bf(float f) {
    union { float f; unsigned int i; } v; v.f = f;
    unsigned int r = v.i + 0x7fff + ((v.i >> 16) & 1);   // round-to-nearest-even
    return (unsigned short)(r >> 16);
}
__device__ __forceinline__ float lo16(unsigned u){ return bf2f((unsigned short)(u & 0xffffu)); }
__device__ __forceinline__ float hi16(unsigned u){ return bf2f((unsigned short)(u >> 16)); }
__device__ __forceinline__ unsigned pack2(float a, float b){
    return (unsigned)f2bf(a) | ((unsigned)f2bf(b) << 16);
}

// ---------------- f32 -> bf16 bulk convert (4 elems/thread) ----------------
__global__ __launch_bounds__(256) void f32_to_bf16(const float* __restrict__ in,
                                                   unsigned short* __restrict__ out) {
    size_t i = ((size_t)blockIdx.x * 256 + threadIdx.x) * 4;
    float4 v = *(const float4*)(in + i);
    uint2 o; o.x = pack2(v.x, v.y); o.y = pack2(v.z, v.w);
    *(uint2*)(out + i) = o;
}

// ---------------- transpose f32 -> bf16: out[c][r] = bf16(in[r][c]) ----------------
__global__ void transpose_f32_bf16(const float* __restrict__ in,
                                   unsigned short* __restrict__ out, int rows, int cols) {
    __shared__ float t[32][33];
    int bx = blockIdx.x * 32, by = blockIdx.y * 32;
    int tx = threadIdx.x, ty = threadIdx.y;
    int r = by + ty, c = bx + tx;
    if (r < rows && c < cols) t[ty][tx] = in[(size_t)r * cols + c];
    __syncthreads();
    int ro = bx + ty, co = by + tx;
    if (ro < cols && co < rows) out[(size_t)ro * rows + co] = f2bf(t[tx][ty]);
}

// ---------------- transpose W_xp cols 1..128: out[j][k] = bf16(wxp[k][1+j]) -------------
// out: [128][2048].  grid (128/32, 2048/32), block (32,32)
__global__ void transpose_wxp(const float* __restrict__ wxp,
                              unsigned short* __restrict__ out) {
    __shared__ float t[32][33];
    int j0 = blockIdx.x * 32, k0 = blockIdx.y * 32;
    int tx = threadIdx.x, ty = threadIdx.y;
    t[ty][tx] = wxp[(size_t)(k0 + ty) * 129 + 1 + j0 + tx];
    __syncthreads();
    out[(size_t)(j0 + ty) * 2048 + k0 + tx] = f2bf(t[tx][ty]);
}

// ---------------- extract w0 (delta weight column) ----------------
__global__ void extract_w0(const float* __restrict__ wxp, float* __restrict__ w0f) {
    int k = blockIdx.x * 256 + threadIdx.x;
    if (k < D_INNER) w0f[k] = wxp[(size_t)k * 129];
}

// ---------------- MFMA GEMM (TN): C[M][N] = A[M][K] @ BT[N][K]^T ----------------
// 128x128 block tile, BK=32, 256 threads (4 waves, 2x2), global_load_lds(16B).
// Requires M%128==0, N%128==0, K%32==0, lda%8==0, ldb%8==0.
#define BM 128
#define BN 128
#define BK 32
enum { EPI_PLAIN = 0, EPI_MUL_XI = 2, EPI_F32OUT = 3 };

__device__ __forceinline__ void gload_lds16(const void* g, void* l) {
    __builtin_amdgcn_global_load_lds((const __attribute__((address_space(1))) void*)g,
                                     (__attribute__((address_space(3))) void*)l, 16, 0, 0);
}

template<int EPI>
__global__ __launch_bounds__(256) void gemm_tn(
    const unsigned short* __restrict__ A,   // [M][K] lda (bf16)
    const unsigned short* __restrict__ BT,  // [N][K] ldb (bf16)
    void* __restrict__ Cv,                  // [M][N] ldc (bf16; f32 if F32OUT)
    const unsigned short* __restrict__ XI, int ldxi,
    int M, int N, int K, int lda, int ldb, int ldc)
{
    __shared__ __align__(16) unsigned short As[BM * BK];
    __shared__ __align__(16) unsigned short Bs[BN * BK];
    const int tid  = threadIdx.x;
    const int wave = tid >> 6, lane = tid & 63;
    const int row0 = blockIdx.y * BM, col0 = blockIdx.x * BN;
    const int wr = (wave >> 1) * 64, wc = (wave & 1) * 64;
    const int srow = lane >> 2;          // 0..15
    const int scol = (lane & 3) * 8;     // 0,8,16,24

    f32x4 acc[4][4];
    #pragma unroll
    for (int i = 0; i < 4; ++i)
        #pragma unroll
        for (int j = 0; j < 4; ++j)
            #pragma unroll
            for (int r = 0; r < 4; ++r) acc[i][j][r] = 0.0f;

    for (int k0 = 0; k0 < K; k0 += BK) {
        #pragma unroll
        for (int qi = 0; qi < 2; ++qi) {
            int q = wave * 2 + qi;   // 0..7: 16-row group of the 128-row tile
            const unsigned short* gA = A  + (size_t)(row0 + q*16 + srow) * lda + (k0 + scol);
            const unsigned short* gB = BT + (size_t)(col0 + q*16 + srow) * ldb + (k0 + scol);
            gload_lds16(gA, &As[q * 512]);   // lane l lands at +l*16B (contiguous row-major)
            gload_lds16(gB, &Bs[q * 512]);
        }
        __syncthreads();
        bf16x8 af[4], bfr[4];
        #pragma unroll
        for (int t = 0; t < 4; ++t) {
            af[t]  = *(const bf16x8*)&As[(wr + t*16 + (lane & 15)) * BK + (lane >> 4) * 8];
            bfr[t] = *(const bf16x8*)&Bs[(wc + t*16 + (lane & 15)) * BK + (lane >> 4) * 8];
        }
        #pragma unroll
        for (int i = 0; i < 4; ++i)
            #pragma unroll
            for (int j = 0; j < 4; ++j)
                acc[i][j] = __builtin_amdgcn_mfma_f32_16x16x32_bf16(af[i], bfr[j], acc[i][j], 0, 0, 0);
        __syncthreads();
    }

    const int r0 = (lane >> 4) * 4, cl = lane & 15;
    #pragma unroll
    for (int i = 0; i < 4; ++i) {
        #pragma unroll
        for (int j = 0; j < 4; ++j) {
            #pragma unroll
            for (int r = 0; r < 4; ++r) {
                int gr = row0 + wr + i*16 + r0 + r;
                int gc = col0 + wc + j*16 + cl;
                float v = acc[i][j][r];
                if (EPI == EPI_MUL_XI) v *= bf2f(XI[(size_t)gr * ldxi + gc]);
                if (EPI == EPI_F32OUT) ((float*)Cv)[(size_t)gr * ldc + gc] = v;
                else                   ((unsigned short*)Cv)[(size_t)gr * ldc + gc] = f2bf(v);
            }
        }
    }
}

// ---------------- delta: dA[m] = softplus(xi[m,:]. w0) * A ; abar = exp(dA) ----------------
__global__ __launch_bounds__(256) void delta_kernel(
    const unsigned short* __restrict__ xz, const float* __restrict__ w0f,
    const float* __restrict__ A_log,
    float* __restrict__ dA, float* __restrict__ abar)
{
    int row  = blockIdx.x * 4 + (threadIdx.x >> 6);
    int lane = threadIdx.x & 63;
    const unsigned short* xi = xz + (size_t)row * (2 * D_INNER);
    float s = 0.f;
    #pragma unroll
    for (int step = 0; step < 4; ++step) {
        int oct = step * 64 + lane;          // 256 octets of 8 bf16
        uint4 u = *(const uint4*)(xi + oct * 8);
        const float4* pw = (const float4*)(w0f + oct * 8);
        float4 wa = pw[0], wb = pw[1];
        s += lo16(u.x)*wa.x + hi16(u.x)*wa.y + lo16(u.y)*wa.z + hi16(u.y)*wa.w
           + lo16(u.z)*wb.x + hi16(u.z)*wb.y + lo16(u.w)*wb.z + hi16(u.w)*wb.w;
    }
    #pragma unroll
    for (int off = 32; off > 0; off >>= 1) s += __shfl_xor(s, off);
    if (lane == 0) {
        float Av = -expf(A_log[0]);
        float d  = (s > 20.f) ? s : log1pf(expf(s));
        float da = d * Av;
        dA[row] = da;
        abar[row] = expf(da);
    }
}

// ---------------- chunk decay products: P[b*NC+j] = exp(sum dA over chunk) ----------------
__global__ void chunk_prod(const float* __restrict__ dA, float* __restrict__ P) {
    int idx = threadIdx.x;                    // 0..255 = b*NCHUNK + j
    float s = 0.f;
    #pragma unroll
    for (int t = 0; t < CHUNK; ++t) s += dA[idx * CHUNK + t];
    P[idx] = expf(s);
}

// ---------------- scan phase 1: per-chunk local scan (h init 0) -> carry ----------------
__global__ __launch_bounds__(256) void scan_local(
    const unsigned short* __restrict__ bxi, const float* __restrict__ abar,
    float* __restrict__ carry)
{
    int cb = blockIdx.x, j = blockIdx.y, b = blockIdx.z;
    int c0 = cb * 1024 + threadIdx.x * 4;
    int srow = b * SEQ + j * CHUNK;
    const float* ab = abar + srow;
    const unsigned short* p = bxi + (size_t)srow * D_INNER + c0;
    float h0 = 0.f, h1 = 0.f, h2 = 0.f, h3 = 0.f;
    #pragma unroll 8
    for (int t = 0; t < CHUNK; ++t) {
        float a = ab[t];
        uint2 u = *(const uint2*)(p + (size_t)t * D_INNER);
        h0 = fmaf(a, h0, lo16(u.x)); h1 = fmaf(a, h1, hi16(u.x));
        h2 = fmaf(a, h2, lo16(u.y)); h3 = fmaf(a, h3, hi16(u.y));
    }
    *(float4*)(carry + ((size_t)(b * NCHUNK + j)) * D_INNER + c0) = make_float4(h0, h1, h2, h3);
}

// ---------------- scan phase 2: inter-chunk scan; carry <- exclusive prefix (h-init) ------
__global__ __launch_bounds__(256) void scan_chunks(float* __restrict__ carry,
                                                   const float* __restrict__ P) {
    int c = blockIdx.x * 256 + threadIdx.x;
    int b = blockIdx.y;
    float H = 0.f;
    for (int j = 0; j < NCHUNK; ++j) {
        size_t idx = ((size_t)(b * NCHUNK + j)) * D_INNER + c;
        float cr = carry[idx];
        carry[idx] = H;                         // exclusive: h-init for chunk j
        H = P[b * NCHUNK + j] * H + cr;
    }
}

// ---------------- scan phase 3: re-scan with init + fused epilogue -> ypre ----------------
// NOTE: ypre aliases bxi (element read happens before write, same thread) -> no restrict
__global__ __launch_bounds__(256) void scan_final(
    const unsigned short* bxi, const unsigned short* __restrict__ cmat,
    const unsigned short* __restrict__ xz, const float* __restrict__ Dvf,
    const float* __restrict__ abar, const float* __restrict__ carry,
    unsigned short* ypre)
{
    int cb = blockIdx.x, j = blockIdx.y, b = blockIdx.z;
    int c0 = cb * 1024 + threadIdx.x * 4;
    int srow = b * SEQ + j * CHUNK;
    float4 hin = *(const float4*)(carry + ((size_t)(b * NCHUNK + j)) * D_INNER + c0);
    float h0 = hin.x, h1 = hin.y, h2 = hin.z, h3 = hin.w;
    float4 dv = *(const float4*)(Dvf + c0);
    float d0 = dv.x, d1 = dv.y, d2 = dv.z, d3 = dv.w;
    const float* ab = abar + srow;
    #pragma unroll 4
    for (int t = 0; t < CHUNK; ++t) {
        size_t m = (size_t)(srow + t);
        float a = ab[t];
        uint2 ub = *(const uint2*)(bxi + m * D_INNER + c0);
        h0 = fmaf(a, h0, lo16(ub.x)); h1 = fmaf(a, h1, hi16(ub.x));
        h2 = fmaf(a, h2, lo16(ub.y)); h3 = fmaf(a, h3, hi16(ub.y));
        uint2 uc = *(const uint2*)(cmat + m * D_INNER + c0);
        uint2 ux = *(const uint2*)(xz + m * (2 * D_INNER) + c0);
        uint2 uz = *(const uint2*)(xz + m * (2 * D_INNER) + D_INNER + c0);
        float y0 = lo16(uc.x) * h0 + d0 * lo16(ux.x);
        float y1 = hi16(uc.x) * h1 + d1 * hi16(ux.x);
        float y2 = lo16(uc.y) * h2 + d2 * lo16(ux.y);
        float y3 = hi16(uc.y) * h3 + d3 * hi16(ux.y);
        float z0 = lo16(uz.x), z1 = hi16(uz.x), z2 = lo16(uz.y), z3 = hi16(uz.y);
        y0 *= z0 / (1.f + expf(-z0)); y1 *= z1 / (1.f + expf(-z1));
        y2 *= z2 / (1.f + expf(-z2)); y3 *= z3 / (1.f + expf(-z3));
        uint2 o; o.x = pack2(y0, y1); o.y = pack2(y2, y3);
        *(uint2*)(ypre + m * D_INNER + c0) = o;
    }
}

// ---------------- launcher ----------------
extern "C" void kernel_launch(void* const* d_in, const int* in_sizes, int n_in,
                              void* d_out, int out_size, void* d_ws, size_t ws_size,
                              hipStream_t stream) {
    const float* x     = (const float*)d_in[0];   // [8192][1024]
    const float* W_in  = (const float*)d_in[1];   // [1024][4096]
    const float* W_xp  = (const float*)d_in[2];   // [2048][129]
    const float* W_B   = (const float*)d_in[3];   // [64][2048]
    const float* W_C   = (const float*)d_in[4];   // [64][2048]
    const float* W_out = (const float*)d_in[5];   // [2048][1024]
    const float* Dv    = (const float*)d_in[6];   // [2048]
    const float* A_log = (const float*)d_in[7];   // [1]
    float* out = (float*)d_out;                   // [8192][1024] f32

    // workspace layout (256B aligned blocks)
    size_t off = 0;
    auto alloc = [&](size_t bytes) {
        void* p = (char*)d_ws + off; off += (bytes + 255) & ~(size_t)255; return p;
    };
    unsigned short* xbf   = (unsigned short*)alloc((size_t)MROWS * D_MODEL * 2);     // 16.8MB
    unsigned short* xz    = (unsigned short*)alloc((size_t)MROWS * 2 * D_INNER * 2); // 67MB
    unsigned short* bxi   = (unsigned short*)alloc((size_t)MROWS * D_INNER * 2);     // 33.5MB (also ypre)
    unsigned short* cmat  = (unsigned short*)alloc((size_t)MROWS * D_INNER * 2);     // 33.5MB
    unsigned short* winT  = (unsigned short*)alloc((size_t)4096 * 1024 * 2);         // 8.4MB
    unsigned short* woutT = (unsigned short*)alloc((size_t)1024 * 2048 * 2);         // 4.2MB
    unsigned short* wbT   = (unsigned short*)alloc((size_t)2048 * 64 * 2);           // [2048][64]
    unsigned short* wcT   = (unsigned short*)alloc((size_t)2048 * 64 * 2);           // [2048][64]
    unsigned short* wxpT  = (unsigned short*)alloc((size_t)128 * 2048 * 2);          // [128][2048]
    unsigned short* projb = (unsigned short*)alloc((size_t)MROWS * 128 * 2);         // [8192][128] (B_raw|C_raw)
    float* w0f   = (float*)alloc(2048 * 4);
    float* dA    = (float*)alloc(MROWS * 4);
    float* abar  = (float*)alloc(MROWS * 4);
    float* P     = (float*)alloc(BATCH * NCHUNK * 4);
    float* carry = (float*)alloc((size_t)BATCH * NCHUNK * D_INNER * 4);              // 2MB
    (void)ws_size; (void)n_in; (void)in_sizes; (void)out_size;

    // convert x to bf16
    hipLaunchKernelGGL(f32_to_bf16, dim3((MROWS * D_MODEL) / 1024), dim3(256), 0, stream, x, xbf);

    dim3 tb(32, 32);
    hipLaunchKernelGGL(transpose_f32_bf16, dim3(4096/32, 1024/32), tb, 0, stream, W_in,  winT, 1024, 4096);
    hipLaunchKernelGGL(transpose_f32_bf16, dim3(1024/32, 2048/32), tb, 0, stream, W_out, woutT, 2048, 1024);
    hipLaunchKernelGGL(transpose_f32_bf16, dim3(2048/32, 64/32),   tb, 0, stream, W_B,   wbT, 64, 2048);
    hipLaunchKernelGGL(transpose_f32_bf16, dim3(2048/32, 64/32),   tb, 0, stream, W_C,   wcT, 64, 2048);
    hipLaunchKernelGGL(transpose_wxp, dim3(4, 64), tb, 0, stream, W_xp, wxpT);
    hipLaunchKernelGGL(extract_w0, dim3(8), dim3(256), 0, stream, W_xp, w0f);

    // xz = x @ W_in   [8192][4096]
    hipLaunchKernelGGL((gemm_tn<EPI_PLAIN>), dim3(4096/BN, MROWS/BM), dim3(256), 0, stream,
                       xbf, winT, (void*)xz, (const unsigned short*)nullptr, 0,
                       MROWS, 4096, 1024, 1024, 1024, 4096);

    // delta / abar
    hipLaunchKernelGGL(delta_kernel, dim3(MROWS/4), dim3(256), 0, stream, xz, w0f, A_log, dA, abar);

    // proj = xi @ W_xp[:,1:129]   [8192][128]  (cols 0..63 = B_raw, 64..127 = C_raw)
    hipLaunchKernelGGL((gemm_tn<EPI_PLAIN>), dim3(1, MROWS/BM), dim3(256), 0, stream,
                       xz, wxpT, (void*)projb, (const unsigned short*)nullptr, 0,
                       MROWS, 128, D_INNER, 2*D_INNER, D_INNER, 128);

    // bxi = (B_raw @ W_B) * xi ;  cmat = C_raw @ W_C    (rank-64 expansion, K=64)
    hipLaunchKernelGGL((gemm_tn<EPI_MUL_XI>), dim3(D_INNER/BN, MROWS/BM), dim3(256), 0, stream,
                       projb, wbT, (void*)bxi, xz, 2*D_INNER,
                       MROWS, D_INNER, 64, 128, 64, D_INNER);
    hipLaunchKernelGGL((gemm_tn<EPI_PLAIN>), dim3(D_INNER/BN, MROWS/BM), dim3(256), 0, stream,
                       projb + 64, wcT, (void*)cmat, (const unsigned short*)nullptr, 0,
                       MROWS, D_INNER, 64, 128, 64, D_INNER);

    // chunked scan + fused epilogue
    hipLaunchKernelGGL(chunk_prod, dim3(1), dim3(BATCH*NCHUNK), 0, stream, dA, P);
    hipLaunchKernelGGL(scan_local,  dim3(2, NCHUNK, BATCH), dim3(256), 0, stream, bxi, abar, carry);
    hipLaunchKernelGGL(scan_chunks, dim3(D_INNER/256, BATCH), dim3(256), 0, stream, carry, P);
    hipLaunchKernelGGL(scan_final,  dim3(2, NCHUNK, BATCH), dim3(256), 0, stream,
                       bxi, cmat, xz, Dv, abar, carry, bxi /*ypre aliases bxi*/);

    // out = ypre @ W_out   [8192][1024] f32
    hipLaunchKernelGGL((gemm_tn<EPI_F32OUT>), dim3(1024/BN, MROWS/BM), dim3(256), 0, stream,
                       bxi, woutT, (void*)out, (const unsigned short*)nullptr, 0,
                       MROWS, 1024, D_INNER, D_INNER, D_INNER, 1024);
}

// Round 4
// 363.125 us; speedup vs baseline: 1.5719x; 1.1014x over previous
//
#include <hip/hip_runtime.h>
#include <hip/hip_bf16.h>
#include <cstdint>
#include <cstddef>

// ---------------- problem constants ----------------
#define D_MODEL 1024
#define D_STATE 64
#define D_INNER 2048
#define BATCH   4
#define SEQ     2048
#define MROWS   (BATCH*SEQ)      // 8192
#define CHUNK   32               // scan chunk length
#define NCHUNK  (SEQ/CHUNK)      // 64 chunks per batch

typedef __bf16 bf16x8 __attribute__((ext_vector_type(8)));
typedef float  f32x4  __attribute__((ext_vector_type(4)));

__device__ __forceinline__ float bf2f(unsigned short u) {
    union { unsigned int i; float f; } v; v.i = ((unsigned int)u) << 16; return v.f;
}
__device__ __forceinline__ unsigned short f2bf(float f) {
    union { float f; unsigned int i; } v; v.f = f;
    unsigned int r = v.i + 0x7fff + ((v.i >> 16) & 1);   // round-to-nearest-even
    return (unsigned short)(r >> 16);
}
__device__ __forceinline__ float lo16(unsigned u){ return bf2f((unsigned short)(u & 0xffffu)); }
__device__ __forceinline__ float hi16(unsigned u){ return bf2f((unsigned short)(u >> 16)); }
__device__ __forceinline__ unsigned pack2(float a, float b){
    return (unsigned)f2bf(a) | ((unsigned)f2bf(b) << 16);
}

// ---------------- f32 -> bf16 bulk convert (4 elems/thread) ----------------
__global__ __launch_bounds__(256) void f32_to_bf16(const float* __restrict__ in,
                                                   unsigned short* __restrict__ out) {
    size_t i = ((size_t)blockIdx.x * 256 + threadIdx.x) * 4;
    float4 v = *(const float4*)(in + i);
    uint2 o; o.x = pack2(v.x, v.y); o.y = pack2(v.z, v.w);
    *(uint2*)(out + i) = o;
}

// ---------------- transpose f32 -> bf16: out[c][r] = bf16(in[r][c]) ----------------
__global__ void transpose_f32_bf16(const float* __restrict__ in,
                                   unsigned short* __restrict__ out, int rows, int cols) {
    __shared__ float t[32][33];
    int bx = blockIdx.x * 32, by = blockIdx.y * 32;
    int tx = threadIdx.x, ty = threadIdx.y;
    int r = by + ty, c = bx + tx;
    if (r < rows && c < cols) t[ty][tx] = in[(size_t)r * cols + c];
    __syncthreads();
    int ro = bx + ty, co = by + tx;
    if (ro < cols && co < rows) out[(size_t)ro * rows + co] = f2bf(t[tx][ty]);
}

// ---------------- transpose W_xp cols 1..128: out[j][k] = bf16(wxp[k][1+j]) -------------
__global__ void transpose_wxp(const float* __restrict__ wxp,
                              unsigned short* __restrict__ out) {
    __shared__ float t[32][33];
    int j0 = blockIdx.x * 32, k0 = blockIdx.y * 32;
    int tx = threadIdx.x, ty = threadIdx.y;
    t[ty][tx] = wxp[(size_t)(k0 + ty) * 129 + 1 + j0 + tx];
    __syncthreads();
    out[(size_t)(j0 + ty) * 2048 + k0 + tx] = f2bf(t[tx][ty]);
}

// ---------------- extract w0 (delta weight column) ----------------
__global__ void extract_w0(const float* __restrict__ wxp, float* __restrict__ w0f) {
    int k = blockIdx.x * 256 + threadIdx.x;
    if (k < D_INNER) w0f[k] = wxp[(size_t)k * 129];
}

// ---------------- MFMA GEMM (TN): C[M][N] = A[M][K] @ BT[N][K]^T ----------------
// 128x128 block tile, BK=64 (two 32-wide LDS buffers per operand: keeps the
// global_load_lds lane-contiguity AND the conflict-free 64B row stride),
// 256 threads (4 waves, 2x2), global_load_lds(16B).
// Requires M%128==0, N%128==0, kchunk%64==0, lda%8==0, ldb%8==0.
// Split-K: blockIdx.z selects K-range [z*kchunk, (z+1)*kchunk); EPI_F32ACC
// writes f32 partials at Cv + z*M*ldc.
#define BM 128
#define BN 128
enum { EPI_PLAIN = 0, EPI_MUL_XI = 2, EPI_F32OUT = 3, EPI_F32ACC = 4 };

__device__ __forceinline__ void gload_lds16(const void* g, void* l) {
    __builtin_amdgcn_global_load_lds((const __attribute__((address_space(1))) void*)g,
                                     (__attribute__((address_space(3))) void*)l, 16, 0, 0);
}

template<int EPI>
__global__ __launch_bounds__(256) void gemm_tn(
    const unsigned short* __restrict__ A,   // [M][K] lda (bf16)
    const unsigned short* __restrict__ BT,  // [N][K] ldb (bf16)
    void* __restrict__ Cv,                  // [M][N] ldc
    const unsigned short* __restrict__ XI, int ldxi,
    int M, int N, int kchunk, int lda, int ldb, int ldc)
{
    __shared__ __align__(16) unsigned short As0[BM * 32];
    __shared__ __align__(16) unsigned short As1[BM * 32];
    __shared__ __align__(16) unsigned short Bs0[BN * 32];
    __shared__ __align__(16) unsigned short Bs1[BN * 32];
    const int tid  = threadIdx.x;
    const int wave = tid >> 6, lane = tid & 63;
    const int row0 = blockIdx.y * BM, col0 = blockIdx.x * BN;
    const int wr = (wave >> 1) * 64, wc = (wave & 1) * 64;
    const int srow = lane >> 2;          // 0..15
    const int scol = (lane & 3) * 8;     // 0,8,16,24

    f32x4 acc[4][4];
    #pragma unroll
    for (int i = 0; i < 4; ++i)
        #pragma unroll
        for (int j = 0; j < 4; ++j)
            #pragma unroll
            for (int r = 0; r < 4; ++r) acc[i][j][r] = 0.0f;

    const int kbeg = blockIdx.z * kchunk;
    for (int k0 = kbeg; k0 < kbeg + kchunk; k0 += 64) {
        #pragma unroll
        for (int qi = 0; qi < 2; ++qi) {
            int q = wave * 2 + qi;   // 0..7: 16-row group of the 128-row tile
            const unsigned short* gA = A  + (size_t)(row0 + q*16 + srow) * lda + (k0 + scol);
            const unsigned short* gB = BT + (size_t)(col0 + q*16 + srow) * ldb + (k0 + scol);
            gload_lds16(gA,      &As0[q * 512]);
            gload_lds16(gA + 32, &As1[q * 512]);
            gload_lds16(gB,      &Bs0[q * 512]);
            gload_lds16(gB + 32, &Bs1[q * 512]);
        }
        __syncthreads();
        bf16x8 af0[4], af1[4], bf0[4], bf1[4];
        const int lro = lane & 15, lko = (lane >> 4) * 8;
        #pragma unroll
        for (int t = 0; t < 4; ++t) {
            af0[t] = *(const bf16x8*)&As0[(wr + t*16 + lro) * 32 + lko];
            af1[t] = *(const bf16x8*)&As1[(wr + t*16 + lro) * 32 + lko];
            bf0[t] = *(const bf16x8*)&Bs0[(wc + t*16 + lro) * 32 + lko];
            bf1[t] = *(const bf16x8*)&Bs1[(wc + t*16 + lro) * 32 + lko];
        }
        #pragma unroll
        for (int i = 0; i < 4; ++i)
            #pragma unroll
            for (int j = 0; j < 4; ++j) {
                acc[i][j] = __builtin_amdgcn_mfma_f32_16x16x32_bf16(af0[i], bf0[j], acc[i][j], 0, 0, 0);
                acc[i][j] = __builtin_amdgcn_mfma_f32_16x16x32_bf16(af1[i], bf1[j], acc[i][j], 0, 0, 0);
            }
        __syncthreads();
    }

    const int r0 = (lane >> 4) * 4, cl = lane & 15;
    #pragma unroll
    for (int i = 0; i < 4; ++i) {
        #pragma unroll
        for (int j = 0; j < 4; ++j) {
            #pragma unroll
            for (int r = 0; r < 4; ++r) {
                int gr = row0 + wr + i*16 + r0 + r;
                int gc = col0 + wc + j*16 + cl;
                float v = acc[i][j][r];
                if (EPI == EPI_MUL_XI) v *= bf2f(XI[(size_t)gr * ldxi + gc]);
                if (EPI == EPI_F32OUT)      ((float*)Cv)[(size_t)gr * ldc + gc] = v;
                else if (EPI == EPI_F32ACC) ((float*)Cv + (size_t)blockIdx.z * M * ldc)[(size_t)gr * ldc + gc] = v;
                else                        ((unsigned short*)Cv)[(size_t)gr * ldc + gc] = f2bf(v);
            }
        }
    }
}

// ---------------- reduce split-K partials -> bf16 ----------------
// in: [4][MROWS][128] f32, out: [MROWS][128] bf16. 4 elems/thread.
__global__ __launch_bounds__(256) void reduce_proj(const float* __restrict__ part,
                                                   unsigned short* __restrict__ out) {
    size_t i = ((size_t)blockIdx.x * 256 + threadIdx.x) * 4;
    const size_t stride = (size_t)MROWS * 128;
    float4 s = *(const float4*)(part + i);
    #pragma unroll
    for (int p = 1; p < 4; ++p) {
        float4 v = *(const float4*)(part + p * stride + i);
        s.x += v.x; s.y += v.y; s.z += v.z; s.w += v.w;
    }
    uint2 o; o.x = pack2(s.x, s.y); o.y = pack2(s.z, s.w);
    *(uint2*)(out + i) = o;
}

// ---------------- delta: dA[m] = softplus(xi[m,:]. w0) * A ; abar = exp(dA) ----------------
__global__ __launch_bounds__(256) void delta_kernel(
    const unsigned short* __restrict__ xz, const float* __restrict__ w0f,
    const float* __restrict__ A_log,
    float* __restrict__ dA, float* __restrict__ abar)
{
    int row  = blockIdx.x * 4 + (threadIdx.x >> 6);
    int lane = threadIdx.x & 63;
    const unsigned short* xi = xz + (size_t)row * (2 * D_INNER);
    float s = 0.f;
    #pragma unroll
    for (int step = 0; step < 4; ++step) {
        int oct = step * 64 + lane;          // 256 octets of 8 bf16
        uint4 u = *(const uint4*)(xi + oct * 8);
        const float4* pw = (const float4*)(w0f + oct * 8);
        float4 wa = pw[0], wb = pw[1];
        s += lo16(u.x)*wa.x + hi16(u.x)*wa.y + lo16(u.y)*wa.z + hi16(u.y)*wa.w
           + lo16(u.z)*wb.x + hi16(u.z)*wb.y + lo16(u.w)*wb.z + hi16(u.w)*wb.w;
    }
    #pragma unroll
    for (int off = 32; off > 0; off >>= 1) s += __shfl_xor(s, off);
    if (lane == 0) {
        float Av = -expf(A_log[0]);
        float d  = (s > 20.f) ? s : log1pf(expf(s));
        float da = d * Av;
        dA[row] = da;
        abar[row] = expf(da);
    }
}

// ---------------- chunk decay products: P[b*NC+j] = exp(sum dA over chunk) ----------------
__global__ void chunk_prod(const float* __restrict__ dA, float* __restrict__ P) {
    int idx = threadIdx.x;                    // 0..255 = b*NCHUNK + j
    float s = 0.f;
    #pragma unroll
    for (int t = 0; t < CHUNK; ++t) s += dA[idx * CHUNK + t];
    P[idx] = expf(s);
}

// ---------------- scan phase 1: per-chunk local scan (h init 0) -> carry ----------------
__global__ __launch_bounds__(256) void scan_local(
    const unsigned short* __restrict__ bxi, const float* __restrict__ abar,
    float* __restrict__ carry)
{
    int cb = blockIdx.x, j = blockIdx.y, b = blockIdx.z;
    int c0 = cb * 1024 + threadIdx.x * 4;
    int srow = b * SEQ + j * CHUNK;
    const float* ab = abar + srow;
    const unsigned short* p = bxi + (size_t)srow * D_INNER + c0;
    float h0 = 0.f, h1 = 0.f, h2 = 0.f, h3 = 0.f;
    #pragma unroll 8
    for (int t = 0; t < CHUNK; ++t) {
        float a = ab[t];
        uint2 u = *(const uint2*)(p + (size_t)t * D_INNER);
        h0 = fmaf(a, h0, lo16(u.x)); h1 = fmaf(a, h1, hi16(u.x));
        h2 = fmaf(a, h2, lo16(u.y)); h3 = fmaf(a, h3, hi16(u.y));
    }
    *(float4*)(carry + ((size_t)(b * NCHUNK + j)) * D_INNER + c0) = make_float4(h0, h1, h2, h3);
}

// ---------------- scan phase 2: inter-chunk scan; carry <- exclusive prefix (h-init) ------
__global__ __launch_bounds__(256) void scan_chunks(float* __restrict__ carry,
                                                   const float* __restrict__ P) {
    int c = blockIdx.x * 256 + threadIdx.x;
    int b = blockIdx.y;
    float H = 0.f;
    for (int j = 0; j < NCHUNK; ++j) {
        size_t idx = ((size_t)(b * NCHUNK + j)) * D_INNER + c;
        float cr = carry[idx];
        carry[idx] = H;                         // exclusive: h-init for chunk j
        H = P[b * NCHUNK + j] * H + cr;
    }
}

// ---------------- scan phase 3: re-scan with init + fused epilogue -> ypre ----------------
// NOTE: ypre aliases bxi (element read happens before write, same thread) -> no restrict
__global__ __launch_bounds__(256) void scan_final(
    const unsigned short* bxi, const unsigned short* __restrict__ cmat,
    const unsigned short* __restrict__ xz, const float* __restrict__ Dvf,
    const float* __restrict__ abar, const float* __restrict__ carry,
    unsigned short* ypre)
{
    int cb = blockIdx.x, j = blockIdx.y, b = blockIdx.z;
    int c0 = cb * 1024 + threadIdx.x * 4;
    int srow = b * SEQ + j * CHUNK;
    float4 hin = *(const float4*)(carry + ((size_t)(b * NCHUNK + j)) * D_INNER + c0);
    float h0 = hin.x, h1 = hin.y, h2 = hin.z, h3 = hin.w;
    float4 dv = *(const float4*)(Dvf + c0);
    float d0 = dv.x, d1 = dv.y, d2 = dv.z, d3 = dv.w;
    const float* ab = abar + srow;
    #pragma unroll 4
    for (int t = 0; t < CHUNK; ++t) {
        size_t m = (size_t)(srow + t);
        float a = ab[t];
        uint2 ub = *(const uint2*)(bxi + m * D_INNER + c0);
        h0 = fmaf(a, h0, lo16(ub.x)); h1 = fmaf(a, h1, hi16(ub.x));
        h2 = fmaf(a, h2, lo16(ub.y)); h3 = fmaf(a, h3, hi16(ub.y));
        uint2 uc = *(const uint2*)(cmat + m * D_INNER + c0);
        uint2 ux = *(const uint2*)(xz + m * (2 * D_INNER) + c0);
        uint2 uz = *(const uint2*)(xz + m * (2 * D_INNER) + D_INNER + c0);
        float y0 = lo16(uc.x) * h0 + d0 * lo16(ux.x);
        float y1 = hi16(uc.x) * h1 + d1 * hi16(ux.x);
        float y2 = lo16(uc.y) * h2 + d2 * lo16(ux.y);
        float y3 = hi16(uc.y) * h3 + d3 * hi16(ux.y);
        float z0 = lo16(uz.x), z1 = hi16(uz.x), z2 = lo16(uz.y), z3 = hi16(uz.y);
        y0 *= z0 / (1.f + expf(-z0)); y1 *= z1 / (1.f + expf(-z1));
        y2 *= z2 / (1.f + expf(-z2)); y3 *= z3 / (1.f + expf(-z3));
        uint2 o; o.x = pack2(y0, y1); o.y = pack2(y2, y3);
        *(uint2*)(ypre + m * D_INNER + c0) = o;
    }
}

// ---------------- launcher ----------------
extern "C" void kernel_launch(void* const* d_in, const int* in_sizes, int n_in,
                              void* d_out, int out_size, void* d_ws, size_t ws_size,
                              hipStream_t stream) {
    const float* x     = (const float*)d_in[0];   // [8192][1024]
    const float* W_in  = (const float*)d_in[1];   // [1024][4096]
    const float* W_xp  = (const float*)d_in[2];   // [2048][129]
    const float* W_B   = (const float*)d_in[3];   // [64][2048]
    const float* W_C   = (const float*)d_in[4];   // [64][2048]
    const float* W_out = (const float*)d_in[5];   // [2048][1024]
    const float* Dv    = (const float*)d_in[6];   // [2048]
    const float* A_log = (const float*)d_in[7];   // [1]
    float* out = (float*)d_out;                   // [8192][1024] f32

    // workspace layout (256B aligned blocks)
    size_t off = 0;
    auto alloc = [&](size_t bytes) {
        void* p = (char*)d_ws + off; off += (bytes + 255) & ~(size_t)255; return p;
    };
    unsigned short* xbf   = (unsigned short*)alloc((size_t)MROWS * D_MODEL * 2);     // 16.8MB
    unsigned short* xz    = (unsigned short*)alloc((size_t)MROWS * 2 * D_INNER * 2); // 67MB
    unsigned short* bxi   = (unsigned short*)alloc((size_t)MROWS * D_INNER * 2);     // 33.5MB (also ypre)
    unsigned short* cmat  = (unsigned short*)alloc((size_t)MROWS * D_INNER * 2);     // 33.5MB
    unsigned short* winT  = (unsigned short*)alloc((size_t)4096 * 1024 * 2);         // 8.4MB
    unsigned short* woutT = (unsigned short*)alloc((size_t)1024 * 2048 * 2);         // 4.2MB
    unsigned short* wbT   = (unsigned short*)alloc((size_t)2048 * 64 * 2);           // [2048][64]
    unsigned short* wcT   = (unsigned short*)alloc((size_t)2048 * 64 * 2);           // [2048][64]
    unsigned short* wxpT  = (unsigned short*)alloc((size_t)128 * 2048 * 2);          // [128][2048]
    unsigned short* projb = (unsigned short*)alloc((size_t)MROWS * 128 * 2);         // [8192][128]
    float* proj_part = (float*)alloc((size_t)4 * MROWS * 128 * 4);                   // 16.8MB
    float* w0f   = (float*)alloc(2048 * 4);
    float* dA    = (float*)alloc(MROWS * 4);
    float* abar  = (float*)alloc(MROWS * 4);
    float* P     = (float*)alloc(BATCH * NCHUNK * 4);
    float* carry = (float*)alloc((size_t)BATCH * NCHUNK * D_INNER * 4);              // 2MB
    (void)ws_size; (void)n_in; (void)in_sizes; (void)out_size;

    // convert x to bf16
    hipLaunchKernelGGL(f32_to_bf16, dim3((MROWS * D_MODEL) / 1024), dim3(256), 0, stream, x, xbf);

    dim3 tb(32, 32);
    hipLaunchKernelGGL(transpose_f32_bf16, dim3(4096/32, 1024/32), tb, 0, stream, W_in,  winT, 1024, 4096);
    hipLaunchKernelGGL(transpose_f32_bf16, dim3(1024/32, 2048/32), tb, 0, stream, W_out, woutT, 2048, 1024);
    hipLaunchKernelGGL(transpose_f32_bf16, dim3(2048/32, 64/32),   tb, 0, stream, W_B,   wbT, 64, 2048);
    hipLaunchKernelGGL(transpose_f32_bf16, dim3(2048/32, 64/32),   tb, 0, stream, W_C,   wcT, 64, 2048);
    hipLaunchKernelGGL(transpose_wxp, dim3(4, 64), tb, 0, stream, W_xp, wxpT);
    hipLaunchKernelGGL(extract_w0, dim3(8), dim3(256), 0, stream, W_xp, w0f);

    // xz = x @ W_in   [8192][4096]
    hipLaunchKernelGGL((gemm_tn<EPI_PLAIN>), dim3(4096/BN, MROWS/BM), dim3(256), 0, stream,
                       xbf, winT, (void*)xz, (const unsigned short*)nullptr, 0,
                       MROWS, 4096, 1024, 1024, 1024, 4096);

    // delta / abar
    hipLaunchKernelGGL(delta_kernel, dim3(MROWS/4), dim3(256), 0, stream, xz, w0f, A_log, dA, abar);

    // proj = xi @ W_xp[:,1:129]  via split-K=4 (f32 partials) + reduce
    hipLaunchKernelGGL((gemm_tn<EPI_F32ACC>), dim3(1, MROWS/BM, 4), dim3(256), 0, stream,
                       xz, wxpT, (void*)proj_part, (const unsigned short*)nullptr, 0,
                       MROWS, 128, 512, 2*D_INNER, D_INNER, 128);
    hipLaunchKernelGGL(reduce_proj, dim3((MROWS * 128) / 1024), dim3(256), 0, stream,
                       proj_part, projb);

    // bxi = (B_raw @ W_B) * xi ;  cmat = C_raw @ W_C    (rank-64 expansion, K=64)
    hipLaunchKernelGGL((gemm_tn<EPI_MUL_XI>), dim3(D_INNER/BN, MROWS/BM), dim3(256), 0, stream,
                       projb, wbT, (void*)bxi, xz, 2*D_INNER,
                       MROWS, D_INNER, 64, 128, 64, D_INNER);
    hipLaunchKernelGGL((gemm_tn<EPI_PLAIN>), dim3(D_INNER/BN, MROWS/BM), dim3(256), 0, stream,
                       projb + 64, wcT, (void*)cmat, (const unsigned short*)nullptr, 0,
                       MROWS, D_INNER, 64, 128, 64, D_INNER);

    // chunked scan + fused epilogue
    hipLaunchKernelGGL(chunk_prod, dim3(1), dim3(BATCH*NCHUNK), 0, stream, dA, P);
    hipLaunchKernelGGL(scan_local,  dim3(2, NCHUNK, BATCH), dim3(256), 0, stream, bxi, abar, carry);
    hipLaunchKernelGGL(scan_chunks, dim3(D_INNER/256, BATCH), dim3(256), 0, stream, carry, P);
    hipLaunchKernelGGL(scan_final,  dim3(2, NCHUNK, BATCH), dim3(256), 0, stream,
                       bxi, cmat, xz, Dv, abar, carry, bxi /*ypre aliases bxi*/);

    // out = ypre @ W_out   [8192][1024] f32
    hipLaunchKernelGGL((gemm_tn<EPI_F32OUT>), dim3(1024/BN, MROWS/BM), dim3(256), 0, stream,
                       bxi, woutT, (void*)out, (const unsigned short*)nullptr, 0,
                       MROWS, 1024, 2048, D_INNER, D_INNER, 1024);
}

// Round 5
// 357.604 us; speedup vs baseline: 1.5962x; 1.0154x over previous
//
#include <hip/hip_runtime.h>
#include <hip/hip_bf16.h>
#include <cstdint>
#include <cstddef>

// ---------------- problem constants ----------------
#define D_MODEL 1024
#define D_STATE 64
#define D_INNER 2048
#define BATCH   4
#define SEQ     2048
#define MROWS   (BATCH*SEQ)      // 8192
#define CHUNK   32               // scan chunk length
#define NCHUNK  (SEQ/CHUNK)      // 64 chunks per batch

typedef __bf16 bf16x8 __attribute__((ext_vector_type(8)));
typedef float  f32x4  __attribute__((ext_vector_type(4)));

__device__ __forceinline__ float bf2f(unsigned short u) {
    union { unsigned int i; float f; } v; v.i = ((unsigned int)u) << 16; return v.f;
}
__device__ __forceinline__ unsigned short f2bf(float f) {
    union { float f; unsigned int i; } v; v.f = f;
    unsigned int r = v.i + 0x7fff + ((v.i >> 16) & 1);   // round-to-nearest-even
    return (unsigned short)(r >> 16);
}
__device__ __forceinline__ float lo16(unsigned u){ return bf2f((unsigned short)(u & 0xffffu)); }
__device__ __forceinline__ float hi16(unsigned u){ return bf2f((unsigned short)(u >> 16)); }
__device__ __forceinline__ unsigned pack2(float a, float b){
    return (unsigned)f2bf(a) | ((unsigned)f2bf(b) << 16);
}

// ---------------- f32 -> bf16 bulk convert (4 elems/thread) ----------------
__global__ __launch_bounds__(256) void f32_to_bf16(const float* __restrict__ in,
                                                   unsigned short* __restrict__ out) {
    size_t i = ((size_t)blockIdx.x * 256 + threadIdx.x) * 4;
    float4 v = *(const float4*)(in + i);
    uint2 o; o.x = pack2(v.x, v.y); o.y = pack2(v.z, v.w);
    *(uint2*)(out + i) = o;
}

// ---------------- transpose f32 -> bf16: out[c][r] = bf16(in[r][c]) ----------------
__global__ void transpose_f32_bf16(const float* __restrict__ in,
                                   unsigned short* __restrict__ out, int rows, int cols) {
    __shared__ float t[32][33];
    int bx = blockIdx.x * 32, by = blockIdx.y * 32;
    int tx = threadIdx.x, ty = threadIdx.y;
    int r = by + ty, c = bx + tx;
    if (r < rows && c < cols) t[ty][tx] = in[(size_t)r * cols + c];
    __syncthreads();
    int ro = bx + ty, co = by + tx;
    if (ro < cols && co < rows) out[(size_t)ro * rows + co] = f2bf(t[tx][ty]);
}

// ---------------- transpose W_xp cols 1..128: out[j][k] = bf16(wxp[k][1+j]) -------------
__global__ void transpose_wxp(const float* __restrict__ wxp,
                              unsigned short* __restrict__ out) {
    __shared__ float t[32][33];
    int j0 = blockIdx.x * 32, k0 = blockIdx.y * 32;
    int tx = threadIdx.x, ty = threadIdx.y;
    t[ty][tx] = wxp[(size_t)(k0 + ty) * 129 + 1 + j0 + tx];
    __syncthreads();
    out[(size_t)(j0 + ty) * 2048 + k0 + tx] = f2bf(t[tx][ty]);
}

// ---------------- extract w0 (delta weight column) ----------------
__global__ void extract_w0(const float* __restrict__ wxp, float* __restrict__ w0f) {
    int k = blockIdx.x * 256 + threadIdx.x;
    if (k < D_INNER) w0f[k] = wxp[(size_t)k * 129];
}

// ---------------- MFMA GEMM (TN): C[M][N] = A[M][K] @ BT[N][K]^T ----------------
// 128x128 block tile, BK=64 (two 32-wide LDS buffers per operand), 256 threads,
// global_load_lds(16B). Split-K via blockIdx.z + EPI_F32ACC partials.
#define BM 128
#define BN 128
enum { EPI_PLAIN = 0, EPI_F32OUT = 3, EPI_F32ACC = 4 };

__device__ __forceinline__ void gload_lds16(const void* g, void* l) {
    __builtin_amdgcn_global_load_lds((const __attribute__((address_space(1))) void*)g,
                                     (__attribute__((address_space(3))) void*)l, 16, 0, 0);
}

template<int EPI>
__global__ __launch_bounds__(256) void gemm_tn(
    const unsigned short* __restrict__ A,   // [M][K] lda (bf16)
    const unsigned short* __restrict__ BT,  // [N][K] ldb (bf16)
    void* __restrict__ Cv,                  // [M][N] ldc
    int M, int N, int kchunk, int lda, int ldb, int ldc)
{
    __shared__ __align__(16) unsigned short As0[BM * 32];
    __shared__ __align__(16) unsigned short As1[BM * 32];
    __shared__ __align__(16) unsigned short Bs0[BN * 32];
    __shared__ __align__(16) unsigned short Bs1[BN * 32];
    const int tid  = threadIdx.x;
    const int wave = tid >> 6, lane = tid & 63;
    const int row0 = blockIdx.y * BM, col0 = blockIdx.x * BN;
    const int wr = (wave >> 1) * 64, wc = (wave & 1) * 64;
    const int srow = lane >> 2;          // 0..15
    const int scol = (lane & 3) * 8;     // 0,8,16,24

    f32x4 acc[4][4];
    #pragma unroll
    for (int i = 0; i < 4; ++i)
        #pragma unroll
        for (int j = 0; j < 4; ++j)
            #pragma unroll
            for (int r = 0; r < 4; ++r) acc[i][j][r] = 0.0f;

    const int kbeg = blockIdx.z * kchunk;
    for (int k0 = kbeg; k0 < kbeg + kchunk; k0 += 64) {
        #pragma unroll
        for (int qi = 0; qi < 2; ++qi) {
            int q = wave * 2 + qi;   // 0..7: 16-row group of the 128-row tile
            const unsigned short* gA = A  + (size_t)(row0 + q*16 + srow) * lda + (k0 + scol);
            const unsigned short* gB = BT + (size_t)(col0 + q*16 + srow) * ldb + (k0 + scol);
            gload_lds16(gA,      &As0[q * 512]);
            gload_lds16(gA + 32, &As1[q * 512]);
            gload_lds16(gB,      &Bs0[q * 512]);
            gload_lds16(gB + 32, &Bs1[q * 512]);
        }
        __syncthreads();
        bf16x8 af0[4], af1[4], bf0[4], bf1[4];
        const int lro = lane & 15, lko = (lane >> 4) * 8;
        #pragma unroll
        for (int t = 0; t < 4; ++t) {
            af0[t] = *(const bf16x8*)&As0[(wr + t*16 + lro) * 32 + lko];
            af1[t] = *(const bf16x8*)&As1[(wr + t*16 + lro) * 32 + lko];
            bf0[t] = *(const bf16x8*)&Bs0[(wc + t*16 + lro) * 32 + lko];
            bf1[t] = *(const bf16x8*)&Bs1[(wc + t*16 + lro) * 32 + lko];
        }
        #pragma unroll
        for (int i = 0; i < 4; ++i)
            #pragma unroll
            for (int j = 0; j < 4; ++j) {
                acc[i][j] = __builtin_amdgcn_mfma_f32_16x16x32_bf16(af0[i], bf0[j], acc[i][j], 0, 0, 0);
                acc[i][j] = __builtin_amdgcn_mfma_f32_16x16x32_bf16(af1[i], bf1[j], acc[i][j], 0, 0, 0);
            }
        __syncthreads();
    }

    const int r0 = (lane >> 4) * 4, cl = lane & 15;
    #pragma unroll
    for (int i = 0; i < 4; ++i) {
        #pragma unroll
        for (int j = 0; j < 4; ++j) {
            #pragma unroll
            for (int r = 0; r < 4; ++r) {
                int gr = row0 + wr + i*16 + r0 + r;
                int gc = col0 + wc + j*16 + cl;
                float v = acc[i][j][r];
                if (EPI == EPI_F32OUT)      ((float*)Cv)[(size_t)gr * ldc + gc] = v;
                else if (EPI == EPI_F32ACC) ((float*)Cv + (size_t)blockIdx.z * M * ldc)[(size_t)gr * ldc + gc] = v;
                else                        ((unsigned short*)Cv)[(size_t)gr * ldc + gc] = f2bf(v);
            }
        }
    }
}

// ---------------- reduce split-K partials -> bf16 ----------------
__global__ __launch_bounds__(256) void reduce_proj(const float* __restrict__ part,
                                                   unsigned short* __restrict__ out) {
    size_t i = ((size_t)blockIdx.x * 256 + threadIdx.x) * 4;
    const size_t stride = (size_t)MROWS * 128;
    float4 s = *(const float4*)(part + i);
    #pragma unroll
    for (int p = 1; p < 4; ++p) {
        float4 v = *(const float4*)(part + p * stride + i);
        s.x += v.x; s.y += v.y; s.z += v.z; s.w += v.w;
    }
    uint2 o; o.x = pack2(s.x, s.y); o.y = pack2(s.z, s.w);
    *(uint2*)(out + i) = o;
}

// ---------------- delta: dA[m] = softplus(xi[m,:]. w0) * A ; abar = exp(dA) ----------------
__global__ __launch_bounds__(256) void delta_kernel(
    const unsigned short* __restrict__ xz, const float* __restrict__ w0f,
    const float* __restrict__ A_log,
    float* __restrict__ dA, float* __restrict__ abar)
{
    int row  = blockIdx.x * 4 + (threadIdx.x >> 6);
    int lane = threadIdx.x & 63;
    const unsigned short* xi = xz + (size_t)row * (2 * D_INNER);
    float s = 0.f;
    #pragma unroll
    for (int step = 0; step < 4; ++step) {
        int oct = step * 64 + lane;          // 256 octets of 8 bf16
        uint4 u = *(const uint4*)(xi + oct * 8);
        const float4* pw = (const float4*)(w0f + oct * 8);
        float4 wa = pw[0], wb = pw[1];
        s += lo16(u.x)*wa.x + hi16(u.x)*wa.y + lo16(u.y)*wa.z + hi16(u.y)*wa.w
           + lo16(u.z)*wb.x + hi16(u.z)*wb.y + lo16(u.w)*wb.z + hi16(u.w)*wb.w;
    }
    #pragma unroll
    for (int off = 32; off > 0; off >>= 1) s += __shfl_xor(s, off);
    if (lane == 0) {
        float Av = -expf(A_log[0]);
        float d  = (s > 20.f) ? s : log1pf(expf(s));
        float da = d * Av;
        dA[row] = da;
        abar[row] = expf(da);
    }
}

// ---------------- chunk aux: per chunk, suffix products sfx[t]=exp(sum_{s>t} dA) and
//                  total P=exp(sum dA). 1 block x 256 threads (256 chunks). ----------------
__global__ void chunk_aux(const float* __restrict__ dA,
                          float* __restrict__ sfx, float* __restrict__ P) {
    int idx = threadIdx.x;                    // chunk id: 0..255 = b*NCHUNK + j
    float suf = 0.f;
    for (int t = CHUNK - 1; t >= 0; --t) {
        sfx[idx * CHUNK + t] = expf(suf);
        suf += dA[idx * CHUNK + t];
    }
    P[idx] = expf(suf);
}

// ============ fused B/C expansion + scan kernels ============
// Block geometry: 128 channels x 64 rows (2 chunks) x batch.
#define CB 128
#define R2 64
#define PST 136   // padded LDS row stride (elems) for 128-wide tiles -> 2-way max conflicts

// ---------------- pass 1: carry[j][c] = sum_t sfx[t] * B[t][c] * xi[t][c] ----------------
__global__ __launch_bounds__(256) void bc_carry(
    const unsigned short* __restrict__ proj,  // [MROWS][128] bf16 (B_raw|C_raw)
    const unsigned short* __restrict__ wbT,   // [2048][64] bf16
    const unsigned short* __restrict__ xz,    // [MROWS][4096] bf16 (xi = cols 0..2047)
    const float* __restrict__ sfx,            // [MROWS]
    float* __restrict__ carry)                // [BATCH*NCHUNK][2048]
{
    __shared__ unsigned short Ps[R2 * PST];   // proj tile (cols 0..127 valid)
    __shared__ unsigned short Xs[R2 * PST];   // xi tile (channel slice)
    const int cb = blockIdx.x, j2 = blockIdx.y, b = blockIdx.z;
    const int c0 = cb * CB;
    const int srow = b * SEQ + j2 * R2;
    const int tid = threadIdx.x, wave = tid >> 6, lane = tid & 63;

    #pragma unroll
    for (int i = 0; i < 4; ++i) {             // stage proj tile 64x128
        int e = i * 2048 + tid * 8, r = e >> 7, c = e & 127;
        uint4 v = *(const uint4*)(proj + (size_t)(srow + r) * 128 + c);
        *(uint4*)&Ps[r * PST + c] = v;
    }
    #pragma unroll
    for (int i = 0; i < 4; ++i) {             // stage xi tile 64x128
        int e = i * 2048 + tid * 8, r = e >> 7, c = e & 127;
        uint4 v = *(const uint4*)(xz + (size_t)(srow + r) * (2*D_INNER) + c0 + c);
        *(uint4*)&Xs[r * PST + c] = v;
    }
    __syncthreads();

    const int mt0 = (wave >> 1) * 2;          // waves 0,1 -> chunk A rows; 2,3 -> chunk B
    const int nb  = (wave & 1) * 64;
    const int lr = lane & 15, lq = lane >> 4;

    f32x4 acc[2][4];
    #pragma unroll
    for (int mi = 0; mi < 2; ++mi)
        #pragma unroll
        for (int ni = 0; ni < 4; ++ni)
            #pragma unroll
            for (int r = 0; r < 4; ++r) acc[mi][ni][r] = 0.0f;

    #pragma unroll
    for (int s = 0; s < 2; ++s) {             // K=64: two k-steps
        bf16x8 af[2], bfr[4];
        #pragma unroll
        for (int mi = 0; mi < 2; ++mi)
            af[mi] = *(const bf16x8*)&Ps[((mt0+mi)*16 + lr) * PST + s*32 + lq*8];
        #pragma unroll
        for (int ni = 0; ni < 4; ++ni)
            bfr[ni] = *(const bf16x8*)(wbT + (size_t)(c0 + nb + ni*16 + lr) * 64 + s*32 + lq*8);
        #pragma unroll
        for (int mi = 0; mi < 2; ++mi)
            #pragma unroll
            for (int ni = 0; ni < 4; ++ni)
                acc[mi][ni] = __builtin_amdgcn_mfma_f32_16x16x32_bf16(af[mi], bfr[ni], acc[mi][ni], 0, 0, 0);
    }

    float w8[2][4];
    #pragma unroll
    for (int mi = 0; mi < 2; ++mi)
        #pragma unroll
        for (int r = 0; r < 4; ++r)
            w8[mi][r] = sfx[srow + (mt0+mi)*16 + lq*4 + r];

    float csum[4];
    #pragma unroll
    for (int ni = 0; ni < 4; ++ni) {
        float s = 0.f;
        #pragma unroll
        for (int mi = 0; mi < 2; ++mi)
            #pragma unroll
            for (int r = 0; r < 4; ++r) {
                int row = (mt0+mi)*16 + lq*4 + r;
                float xv = bf2f(Xs[row * PST + nb + ni*16 + lr]);
                s += w8[mi][r] * acc[mi][ni][r] * xv;
            }
        s += __shfl_xor(s, 16);
        s += __shfl_xor(s, 32);
        csum[ni] = s;
    }
    if (lane < 16) {
        int jj = j2 * 2 + (mt0 >> 1);
        float* dst = carry + ((size_t)(b * NCHUNK + jj)) * D_INNER + c0 + nb;
        #pragma unroll
        for (int ni = 0; ni < 4; ++ni) dst[ni*16 + lane] = csum[ni];
    }
}

// ---------------- pass 2: inter-chunk scan; carry <- exclusive prefix (h-init) ------
__global__ __launch_bounds__(256) void scan_chunks(float* __restrict__ carry,
                                                   const float* __restrict__ P) {
    int c = blockIdx.x * 256 + threadIdx.x;
    int b = blockIdx.y;
    float H = 0.f;
    for (int j = 0; j < NCHUNK; ++j) {
        size_t idx = ((size_t)(b * NCHUNK + j)) * D_INNER + c;
        float cr = carry[idx];
        carry[idx] = H;                         // exclusive: h-init for chunk j
        H = P[b * NCHUNK + j] * H + cr;
    }
}

// ---------------- pass 3: recompute B,C tiles -> LDS; sequential scan + epilogue -> ypre --
__global__ __launch_bounds__(256) void bc_scan(
    const unsigned short* __restrict__ proj,
    const unsigned short* __restrict__ wbT,   // [2048][64]
    const unsigned short* __restrict__ wcT,   // [2048][64]
    const unsigned short* __restrict__ xz,
    const float* __restrict__ Dvf,
    const float* __restrict__ abar,
    const float* __restrict__ carry,
    unsigned short* __restrict__ ypre)        // [MROWS][2048]
{
    __shared__ unsigned short Ps[R2 * PST];
    __shared__ unsigned short Bt[R2 * PST];
    __shared__ unsigned short Ct[R2 * PST];
    const int cb = blockIdx.x, j2 = blockIdx.y, b = blockIdx.z;
    const int c0 = cb * CB;
    const int srow = b * SEQ + j2 * R2;
    const int tid = threadIdx.x, wave = tid >> 6, lane = tid & 63;

    #pragma unroll
    for (int i = 0; i < 4; ++i) {
        int e = i * 2048 + tid * 8, r = e >> 7, c = e & 127;
        uint4 v = *(const uint4*)(proj + (size_t)(srow + r) * 128 + c);
        *(uint4*)&Ps[r * PST + c] = v;
    }
    __syncthreads();

    const int mt0 = (wave >> 1) * 2;
    const int nb  = (wave & 1) * 64;
    const int lr = lane & 15, lq = lane >> 4;

    #pragma unroll
    for (int mat = 0; mat < 2; ++mat) {
        const unsigned short* W = mat ? wcT : wbT;
        unsigned short* dst = mat ? Ct : Bt;
        const int koff = mat ? 64 : 0;        // proj cols: B_raw 0..63, C_raw 64..127
        f32x4 acc[2][4];
        #pragma unroll
        for (int mi = 0; mi < 2; ++mi)
            #pragma unroll
            for (int ni = 0; ni < 4; ++ni)
                #pragma unroll
                for (int r = 0; r < 4; ++r) acc[mi][ni][r] = 0.0f;
        #pragma unroll
        for (int s = 0; s < 2; ++s) {
            bf16x8 af[2], bfr[4];
            #pragma unroll
            for (int mi = 0; mi < 2; ++mi)
                af[mi] = *(const bf16x8*)&Ps[((mt0+mi)*16 + lr) * PST + koff + s*32 + lq*8];
            #pragma unroll
            for (int ni = 0; ni < 4; ++ni)
                bfr[ni] = *(const bf16x8*)(W + (size_t)(c0 + nb + ni*16 + lr) * 64 + s*32 + lq*8);
            #pragma unroll
            for (int mi = 0; mi < 2; ++mi)
                #pragma unroll
                for (int ni = 0; ni < 4; ++ni)
                    acc[mi][ni] = __builtin_amdgcn_mfma_f32_16x16x32_bf16(af[mi], bfr[ni], acc[mi][ni], 0, 0, 0);
        }
        #pragma unroll
        for (int mi = 0; mi < 2; ++mi)
            #pragma unroll
            for (int ni = 0; ni < 4; ++ni)
                #pragma unroll
                for (int r = 0; r < 4; ++r) {
                    int row = (mt0+mi)*16 + lq*4 + r;
                    dst[row * PST + nb + ni*16 + lr] = f2bf(acc[mi][ni][r]);
                }
    }
    __syncthreads();

    // sequential scan: thread -> (channel, chunk-half)
    const int c  = tid & 127;
    const int hh = tid >> 7;                  // 0 = chunk A (rows 0..31), 1 = chunk B
    const int jj = j2 * 2 + hh;
    const int r0 = hh * 32;
    float h  = carry[((size_t)(b * NCHUNK + jj)) * D_INNER + c0 + c];
    float dv = Dvf[c0 + c];
    for (int t = 0; t < CHUNK; ++t) {
        int row = r0 + t;
        size_t m = (size_t)(srow + row);
        float a  = abar[m];
        float xv = bf2f(xz[m * (2*D_INNER) + c0 + c]);
        float zv = bf2f(xz[m * (2*D_INNER) + D_INNER + c0 + c]);
        float bv = bf2f(Bt[row * PST + c]);
        float cv = bf2f(Ct[row * PST + c]);
        h = fmaf(a, h, bv * xv);
        float y = cv * h + dv * xv;
        y *= zv / (1.f + expf(-zv));
        ypre[m * D_INNER + c0 + c] = f2bf(y);
    }
}

// ---------------- launcher ----------------
extern "C" void kernel_launch(void* const* d_in, const int* in_sizes, int n_in,
                              void* d_out, int out_size, void* d_ws, size_t ws_size,
                              hipStream_t stream) {
    const float* x     = (const float*)d_in[0];   // [8192][1024]
    const float* W_in  = (const float*)d_in[1];   // [1024][4096]
    const float* W_xp  = (const float*)d_in[2];   // [2048][129]
    const float* W_B   = (const float*)d_in[3];   // [64][2048]
    const float* W_C   = (const float*)d_in[4];   // [64][2048]
    const float* W_out = (const float*)d_in[5];   // [2048][1024]
    const float* Dv    = (const float*)d_in[6];   // [2048]
    const float* A_log = (const float*)d_in[7];   // [1]
    float* out = (float*)d_out;                   // [8192][1024] f32

    size_t off = 0;
    auto alloc = [&](size_t bytes) {
        void* p = (char*)d_ws + off; off += (bytes + 255) & ~(size_t)255; return p;
    };
    unsigned short* xbf   = (unsigned short*)alloc((size_t)MROWS * D_MODEL * 2);     // 16.8MB
    unsigned short* xz    = (unsigned short*)alloc((size_t)MROWS * 2 * D_INNER * 2); // 67MB
    unsigned short* ypre  = (unsigned short*)alloc((size_t)MROWS * D_INNER * 2);     // 33.5MB
    unsigned short* winT  = (unsigned short*)alloc((size_t)4096 * 1024 * 2);         // 8.4MB
    unsigned short* woutT = (unsigned short*)alloc((size_t)1024 * 2048 * 2);         // 4.2MB
    unsigned short* wbT   = (unsigned short*)alloc((size_t)2048 * 64 * 2);           // [2048][64]
    unsigned short* wcT   = (unsigned short*)alloc((size_t)2048 * 64 * 2);           // [2048][64]
    unsigned short* wxpT  = (unsigned short*)alloc((size_t)128 * 2048 * 2);          // [128][2048]
    unsigned short* projb = (unsigned short*)alloc((size_t)MROWS * 128 * 2);         // [8192][128]
    float* proj_part = (float*)alloc((size_t)4 * MROWS * 128 * 4);                   // 16.8MB
    float* w0f   = (float*)alloc(2048 * 4);
    float* dA    = (float*)alloc(MROWS * 4);
    float* abar  = (float*)alloc(MROWS * 4);
    float* sfx   = (float*)alloc(MROWS * 4);
    float* P     = (float*)alloc(BATCH * NCHUNK * 4);
    float* carry = (float*)alloc((size_t)BATCH * NCHUNK * D_INNER * 4);              // 2MB
    (void)ws_size; (void)n_in; (void)in_sizes; (void)out_size;

    // convert x to bf16
    hipLaunchKernelGGL(f32_to_bf16, dim3((MROWS * D_MODEL) / 1024), dim3(256), 0, stream, x, xbf);

    dim3 tb(32, 32);
    hipLaunchKernelGGL(transpose_f32_bf16, dim3(4096/32, 1024/32), tb, 0, stream, W_in,  winT, 1024, 4096);
    hipLaunchKernelGGL(transpose_f32_bf16, dim3(1024/32, 2048/32), tb, 0, stream, W_out, woutT, 2048, 1024);
    hipLaunchKernelGGL(transpose_f32_bf16, dim3(2048/32, 64/32),   tb, 0, stream, W_B,   wbT, 64, 2048);
    hipLaunchKernelGGL(transpose_f32_bf16, dim3(2048/32, 64/32),   tb, 0, stream, W_C,   wcT, 64, 2048);
    hipLaunchKernelGGL(transpose_wxp, dim3(4, 64), tb, 0, stream, W_xp, wxpT);
    hipLaunchKernelGGL(extract_w0, dim3(8), dim3(256), 0, stream, W_xp, w0f);

    // xz = x @ W_in   [8192][4096]
    hipLaunchKernelGGL((gemm_tn<EPI_PLAIN>), dim3(4096/BN, MROWS/BM), dim3(256), 0, stream,
                       xbf, winT, (void*)xz, MROWS, 4096, 1024, 1024, 1024, 4096);

    // delta / abar, then per-chunk suffix products
    hipLaunchKernelGGL(delta_kernel, dim3(MROWS/4), dim3(256), 0, stream, xz, w0f, A_log, dA, abar);
    hipLaunchKernelGGL(chunk_aux, dim3(1), dim3(BATCH*NCHUNK), 0, stream, dA, sfx, P);

    // proj = xi @ W_xp[:,1:129]  via split-K=4 (f32 partials) + reduce
    hipLaunchKernelGGL((gemm_tn<EPI_F32ACC>), dim3(1, MROWS/BM, 4), dim3(256), 0, stream,
                       xz, wxpT, (void*)proj_part, MROWS, 128, 512, 2*D_INNER, D_INNER, 128);
    hipLaunchKernelGGL(reduce_proj, dim3((MROWS * 128) / 1024), dim3(256), 0, stream,
                       proj_part, projb);

    // fused expansion + chunked scan
    hipLaunchKernelGGL(bc_carry, dim3(D_INNER/CB, SEQ/R2, BATCH), dim3(256), 0, stream,
                       projb, wbT, xz, sfx, carry);
    hipLaunchKernelGGL(scan_chunks, dim3(D_INNER/256, BATCH), dim3(256), 0, stream, carry, P);
    hipLaunchKernelGGL(bc_scan, dim3(D_INNER/CB, SEQ/R2, BATCH), dim3(256), 0, stream,
                       projb, wbT, wcT, xz, Dv, abar, carry, ypre);

    // out = ypre @ W_out   [8192][1024] f32
    hipLaunchKernelGGL((gemm_tn<EPI_F32OUT>), dim3(1024/BN, MROWS/BM), dim3(256), 0, stream,
                       ypre, woutT, (void*)out, MROWS, 1024, 2048, D_INNER, D_INNER, 1024);
}